// Round 5
// baseline (74.812 us; speedup 1.0000x reference)
//
#include <hip/hip_runtime.h>
#include <math.h>

// Tropical (min-plus) matmul: out[b,o] = min_j (x[b,j] + w[o,j])
// x: [512, 512] f32, w: [1024, 512] f32, out: [512, 1024] f32
//
// Model (reconciled R2-R4): harness floor ~61us (poison fill 40us + restores
// + graph overhead); kernel R3~=R4~=13us. DS-inst throughput is the kernel
// limiter (b128 ~8cyc, one LDS pipe/CU); R4's 0.125 DS/MAC win was eaten by
// k-split overheads (combine + 2-chunk staging + partial traffic).
// R5: keep KSPLIT=4 / 64x64 tile / 4x4 strided thread tile (0.125 DS/MAC,
// <=2-way bank conflicts) but stage the whole K=128 slice ONCE: a single
// __syncthreads() per kernel, no chunk loop. LDS 67.6KB/block, 2 blocks/CU.

typedef float v2f __attribute__((ext_vector_type(2)));

#define B_    512
#define IN_   512
#define OUT_  1024
#define TBB   64    // b rows per block
#define TOO   64    // o cols per block
#define KS    128   // K depth per block (= IN_/KSPLIT)
#define KSPLIT 4
#define PADW  132   // 528B row stride: %16==0 (b128-aligned); 132%32=4 ->
                    // rows tb+16s map pairwise 2-way on banks (free, m136)

__global__ __launch_bounds__(256, 2) void tropical_main(
    const float* __restrict__ x, const float* __restrict__ w,
    float* __restrict__ part)
{
    __shared__ float xs[TBB * PADW];   // xs[row][j], j = 0..127
    __shared__ float ws[TOO * PADW];

    const int tid = threadIdx.x;
    const int b0 = blockIdx.x * TBB;   // 8 tiles
    const int o0 = blockIdx.y * TOO;   // 16 tiles
    const int kz = blockIdx.z;         // 4 k-slices
    const int kbase = kz * KS;

    // staging: tile = 64 rows x 32 float4s = 2048 float4s; 8 per thread
    const int scol = tid & 31;         // float4 column 0..31
    const int srow0 = tid >> 5;        // row 0..7, +8 per pass

    // compute: strided 4x4 tile; rows tb+16s (x), cols to+16s (w)
    const int to = tid & 15;
    const int tb = tid >> 4;

    // ---- stage x and w tiles (coalesced float4 -> b128 LDS stores) ----
#pragma unroll
    for (int p = 0; p < 8; ++p) {
        const int r = srow0 + p * 8;
        const float4 v = *(const float4*)&x[(size_t)(b0 + r) * IN_ + kbase + scol * 4];
        *(float4*)&xs[r * PADW + scol * 4] = v;
    }
#pragma unroll
    for (int p = 0; p < 8; ++p) {
        const int r = srow0 + p * 8;
        const float4 v = *(const float4*)&w[(size_t)(o0 + r) * IN_ + kbase + scol * 4];
        *(float4*)&ws[r * PADW + scol * 4] = v;
    }

    float acc[4][4];
#pragma unroll
    for (int i = 0; i < 4; ++i)
#pragma unroll
        for (int o = 0; o < 4; ++o)
            acc[i][o] = INFINITY;

    __syncthreads();   // the only barrier in the kernel

    // ---- main loop: per 4j, 8x ds_read_b128 -> 64 MACs (1.0 VALU/MAC) ----
#pragma unroll 2
    for (int j = 0; j < KS; j += 4) {
        float4 xv[4], wv[4];
#pragma unroll
        for (int s = 0; s < 4; ++s)
            xv[s] = *(const float4*)&xs[(tb + 16 * s) * PADW + j];
#pragma unroll
        for (int s = 0; s < 4; ++s)
            wv[s] = *(const float4*)&ws[(to + 16 * s) * PADW + j];
#pragma unroll
        for (int i = 0; i < 4; ++i)
#pragma unroll
            for (int o = 0; o < 4; ++o) {
                v2f t0 = (v2f){xv[i].x, xv[i].y} + (v2f){wv[o].x, wv[o].y};
                v2f t1 = (v2f){xv[i].z, xv[i].w} + (v2f){wv[o].z, wv[o].w};
                acc[i][o] = fminf(fminf(acc[i][o], t0.x), t0.y);  // v_min3
                acc[i][o] = fminf(fminf(acc[i][o], t1.x), t1.y);
            }
    }

    // ---- epilogue: partial mins to d_ws slice kz ----
    float* p = part + (size_t)kz * B_ * OUT_;
#pragma unroll
    for (int i = 0; i < 4; ++i) {
        const int row = b0 + tb + 16 * i;
#pragma unroll
        for (int o = 0; o < 4; ++o)
            p[(size_t)row * OUT_ + o0 + to + 16 * o] = acc[i][o];
    }
}

__global__ __launch_bounds__(256) void tropical_combine(
    const float* __restrict__ part, float* __restrict__ out)
{
    const int idx = (blockIdx.x * 256 + threadIdx.x) * 4;
    const size_t N = (size_t)B_ * OUT_;
    float4 a = *(const float4*)&part[idx];
#pragma unroll
    for (int z = 1; z < KSPLIT; ++z) {
        const float4 b = *(const float4*)&part[z * N + idx];
        a.x = fminf(a.x, b.x);
        a.y = fminf(a.y, b.y);
        a.z = fminf(a.z, b.z);
        a.w = fminf(a.w, b.w);
    }
    *(float4*)&out[idx] = a;
}

extern "C" void kernel_launch(void* const* d_in, const int* in_sizes, int n_in,
                              void* d_out, int out_size, void* d_ws, size_t ws_size,
                              hipStream_t stream) {
    const float* x = (const float*)d_in[0];   // [512, 512]
    const float* w = (const float*)d_in[1];   // [1024, 512]
    float* out = (float*)d_out;               // [512, 1024]
    float* part = (float*)d_ws;               // 4 x 512 x 1024 f32 = 8 MB

    dim3 grid(B_ / TBB, OUT_ / TOO, KSPLIT);  // 8 x 16 x 4 = 512 blocks
    tropical_main<<<grid, 256, 0, stream>>>(x, w, part);

    const int nvec = (B_ * OUT_) / 4;         // 131072 float4s
    tropical_combine<<<nvec / 256, 256, 0, stream>>>(part, out);
}